// Round 1
// baseline (917.296 us; speedup 1.0000x reference)
//
#include <hip/hip_runtime.h>
#include <hip/hip_bf16.h>
#include <math.h>

typedef __attribute__((ext_vector_type(8))) __bf16 bf16x8;
typedef __attribute__((ext_vector_type(4))) float f32x4;

#define HH 256
#define WW 256
#define SCALEF 0.08838834764831845f  // 128^-0.5

// ---------------------------------------------------------------------------
// K1: NCHW f32 -> NHWC bf16 transpose
// ---------------------------------------------------------------------------
__global__ __launch_bounds__(256) void transpose_nhwc(const float* __restrict__ in,
                                                      __hip_bfloat16* __restrict__ out)
{
    int blk = blockIdx.x;
    int c0 = (blk & 3) * 32;
    int x0 = ((blk >> 2) & 7) * 32;
    int by = blk >> 5;              // b*256 + y
    int y = by & 255, b = by >> 8;
    __shared__ float tile[32][33];
    int tx = threadIdx.x & 31, ty = threadIdx.x >> 5;   // ty 0..7
#pragma unroll
    for (int i = 0; i < 4; i++) {
        int c = c0 + ty + 8 * i;
        tile[ty + 8 * i][tx] = in[(((size_t)b * 128 + c) * HH + y) * WW + x0 + tx];
    }
    __syncthreads();
#pragma unroll
    for (int i = 0; i < 4; i++) {
        int x = x0 + ty + 8 * i;
        out[(((size_t)b * HH + y) * WW + x) * 128 + c0 + tx] =
            __float2bfloat16(tile[tx][ty + 8 * i]);
    }
}

// ---------------------------------------------------------------------------
// K2: weight repack (co,ci,ky,kx) f32 -> W2[co][ (ky*3+kx)*128 + ci ] bf16
// ---------------------------------------------------------------------------
__global__ __launch_bounds__(256) void prep_w(const float* __restrict__ wq,
                                              const float* __restrict__ wk,
                                              __hip_bfloat16* __restrict__ w2q,
                                              __hip_bfloat16* __restrict__ w2k)
{
    int i = blockIdx.x * 256 + threadIdx.x;
    if (i >= 128 * 128 * 9) return;
    int co = i / (128 * 9);
    int r = i - co * 128 * 9;
    int ci = r / 9;
    int t = r - ci * 9;
    int dst = co * 1152 + t * 128 + ci;
    w2q[dst] = __float2bfloat16(wq[i]);
    w2k[dst] = __float2bfloat16(wk[i]);
}

// ---------------------------------------------------------------------------
// K3: conv3x3 (SAME) as implicit GEMM with MFMA bf16.
// Block: 8x8 pixel tile, all 128 co. 4 waves, wave w owns co [32w,32w+32).
// ---------------------------------------------------------------------------
#define CPAD 152   // 128 + 24 pad: 304B rows, 16B-aligned, ~2-way banks
__global__ __launch_bounds__(256, 4) void conv3x3_mfma(
    const __hip_bfloat16* __restrict__ in0, const __hip_bfloat16* __restrict__ in1,
    const __hip_bfloat16* __restrict__ w2q, const __hip_bfloat16* __restrict__ w2k,
    const float* __restrict__ bq, const float* __restrict__ bk,
    __hip_bfloat16* __restrict__ q0, __hip_bfloat16* __restrict__ k0,
    __hip_bfloat16* __restrict__ q2, __hip_bfloat16* __restrict__ k2)
{
    const int cid = blockIdx.y;
    const __hip_bfloat16* src = (cid >= 2) ? in1 : in0;
    const __hip_bfloat16* wmat = (cid & 1) ? w2k : w2q;
    const float* bias = (cid & 1) ? bk : bq;
    __hip_bfloat16* dst = (cid == 0) ? q0 : (cid == 1) ? k0 : (cid == 2) ? q2 : k2;

    const int pix = blockIdx.x;           // 0..2047
    const int b = pix >> 10;
    const int rr = pix & 1023;
    const int y0 = (rr >> 5) << 3;
    const int x0 = (rr & 31) << 3;

    __shared__ __align__(16) __hip_bfloat16 patch[100 * CPAD];

    for (int idx = threadIdx.x; idx < 1600; idx += 256) {
        int p = idx >> 4, lc = idx & 15;
        int py = p / 10, px = p - py * 10;
        int gy = y0 + py - 1, gx = x0 + px - 1;
        uint4 v = make_uint4(0u, 0u, 0u, 0u);
        if (gy >= 0 && gy < HH && gx >= 0 && gx < WW)
            v = *(const uint4*)(src + ((((size_t)b * HH + gy) * WW + gx) << 7) + lc * 8);
        *(uint4*)(patch + p * CPAD + lc * 8) = v;
    }
    __syncthreads();

    const int lane = threadIdx.x & 63;
    const int wv = threadIdx.x >> 6;
    const int l15 = lane & 15;
    const int kq = lane >> 4;

    f32x4 acc[4][2];
#pragma unroll
    for (int mi = 0; mi < 4; mi++)
#pragma unroll
        for (int n = 0; n < 2; n++) acc[mi][n] = (f32x4){0.f, 0.f, 0.f, 0.f};

    const __hip_bfloat16* wcol0 = wmat + (size_t)(wv * 32 + l15) * 1152;
    const __hip_bfloat16* wcol1 = wmat + (size_t)(wv * 32 + 16 + l15) * 1152;

    for (int t = 0; t < 9; ++t) {
        int ky = t / 3, kx = t - ky * 3;
#pragma unroll
        for (int cc = 0; cc < 4; ++cc) {
            int k = t * 128 + cc * 32 + kq * 8;
            bf16x8 b0 = *(const bf16x8*)(wcol0 + k);
            bf16x8 b1 = *(const bf16x8*)(wcol1 + k);
#pragma unroll
            for (int mi = 0; mi < 4; ++mi) {
                int m = mi * 16 + l15;
                int my = m >> 3, mx = m & 7;
                bf16x8 a = *(const bf16x8*)(patch + ((my + ky) * 10 + (mx + kx)) * CPAD + cc * 32 + kq * 8);
                acc[mi][0] = __builtin_amdgcn_mfma_f32_16x16x32_bf16(a, b0, acc[mi][0], 0, 0, 0);
                acc[mi][1] = __builtin_amdgcn_mfma_f32_16x16x32_bf16(a, b1, acc[mi][1], 0, 0, 0);
            }
        }
    }

    float bv0 = bias[wv * 32 + l15];
    float bv1 = bias[wv * 32 + 16 + l15];
#pragma unroll
    for (int mi = 0; mi < 4; ++mi) {
#pragma unroll
        for (int r = 0; r < 4; ++r) {
            int m = mi * 16 + kq * 4 + r;
            int my = m >> 3, mx = m & 7;
            size_t base = (((size_t)b * HH + (y0 + my)) * WW + (x0 + mx)) << 7;
            dst[base + wv * 32 + l15] = __float2bfloat16(acc[mi][0][r] + bv0);
            dst[base + wv * 32 + 16 + l15] = __float2bfloat16(acc[mi][1][r] + bv1);
        }
    }
}

// ---------------------------------------------------------------------------
// K4: per-(window, estimate x shift) correlation + flow_bsd + flow_mid
// writes spliced+rolled flow fields directly.
// ---------------------------------------------------------------------------
__global__ __launch_bounds__(256, 2) void window_flow(
    const __hip_bfloat16* __restrict__ q0, const __hip_bfloat16* __restrict__ k0,
    const __hip_bfloat16* __restrict__ q2, const __hip_bfloat16* __restrict__ k2,
    const float* __restrict__ btab,
    float* __restrict__ f1e0, float* __restrict__ f1e1,
    float* __restrict__ f0e0, float* __restrict__ f0e1)
{
    const int combo = blockIdx.y;            // 0..7
    const int e = combo >> 2;
    const int sflag = combo & 3;
    const int shq = (sflag >> 1) & 1;        // shift_h flag == quadrant y
    const int swq = sflag & 1;               // shift_w flag == quadrant x
    const int sh = shq ? 4 : 0, sw = swq ? 4 : 0;
    const __hip_bfloat16* qf = e ? q2 : q0;
    const __hip_bfloat16* kf = e ? k0 : k2;
    float* f1 = e ? f1e1 : f1e0;
    float* f0 = e ? f0e1 : f0e0;

    const int wdx = blockIdx.x;              // 0..2047
    const int b = wdx >> 10;
    const int s1i = (wdx >> 5) & 31;
    const int s2i = wdx & 31;

    __shared__ __align__(16) __hip_bfloat16 qt[64 * CPAD];
    __shared__ __align__(16) __hip_bfloat16 kt[64 * CPAD];
    __shared__ float cls[64 * 67];
    __shared__ float cmid[81], fxm[81], fym[81];
    __shared__ float sb[225];

    const int tid = threadIdx.x;
    if (tid < 225) sb[tid] = btab[tid];

    for (int idx = tid; idx < 2048; idx += 256) {
        int which = idx >> 10;
        int p = (idx >> 4) & 63, lc = idx & 15;
        int iy = p >> 3, ix = p & 7;
        int gy = (s1i * 8 + iy + sh) & 255;
        int gx = (s2i * 8 + ix + sw) & 255;
        const __hip_bfloat16* srcf = which ? kf : qf;
        uint4 v = *(const uint4*)(srcf + ((((size_t)b * HH + gy) * WW + gx) << 7) + lc * 8);
        __hip_bfloat16* dstt = which ? kt : qt;
        *(uint4*)(dstt + p * CPAD + lc * 8) = v;
    }
    __syncthreads();

    // corr = qw . kw^T   (M=64, N=64, K=128), 4 waves over M
    const int lane = tid & 63;
    const int wv = tid >> 6;
    const int l15 = lane & 15;
    const int kq = lane >> 4;

    f32x4 acc[4];
#pragma unroll
    for (int nf = 0; nf < 4; nf++) acc[nf] = (f32x4){0.f, 0.f, 0.f, 0.f};

#pragma unroll
    for (int kc = 0; kc < 4; ++kc) {
        bf16x8 a = *(const bf16x8*)(qt + (wv * 16 + l15) * CPAD + kc * 32 + kq * 8);
#pragma unroll
        for (int nf = 0; nf < 4; ++nf) {
            bf16x8 bb = *(const bf16x8*)(kt + (nf * 16 + l15) * CPAD + kc * 32 + kq * 8);
            acc[nf] = __builtin_amdgcn_mfma_f32_16x16x32_bf16(a, bb, acc[nf], 0, 0, 0);
        }
    }

    // epilogue: scale + relative-pos bias + shift mask -> cls
#pragma unroll
    for (int nf = 0; nf < 4; ++nf) {
#pragma unroll
        for (int r = 0; r < 4; ++r) {
            int row = wv * 16 + kq * 4 + r;
            int col = nf * 16 + l15;
            int qy = row >> 3, qx = row & 7;
            int ty = col >> 3, tx = col & 7;
            float v = acc[nf][r] * SCALEF + sb[(qy - ty + 7) * 15 + (qx - tx + 7)];
            if (sflag) {
                int rhq = 0, rwq = 0, rht = 0, rwt = 0;
                if (shq && s1i == 31) { rhq = (qy < 4) ? 1 : 2; rht = (ty < 4) ? 1 : 2; }
                if (swq && s2i == 31) { rwq = (qx < 4) ? 1 : 2; rwt = (tx < 4) ? 1 : 2; }
                int regq, regt;
                if (shq && swq) { regq = rhq * 3 + rwq; regt = rht * 3 + rwt; }
                else if (shq)   { regq = rhq; regt = rht; }
                else            { regq = rwq; regt = rwt; }
                if (regq != regt) v -= 10000.0f;
            }
            cls[row * 67 + col] = v;
        }
    }
    __syncthreads();

    // flow_bsd (16 rows) and flow_mid row softmaxes (81 rows)
    if (tid < 16) {
        int fy = tid >> 2, fx = tid & 3;
        int qy = fy + 2, qx = fx + 2;
        const float* rowp = &cls[(qy * 8 + qx) * 67];
        float mx = -1e30f;
        for (int t = 0; t < 64; ++t) mx = fmaxf(mx, rowp[t]);
        float S = 0.f, sx = 0.f, sy = 0.f;
        for (int t = 0; t < 64; ++t) {
            float p = __expf(rowp[t] - mx);
            S += p; sx += p * (float)(t & 7); sy += p * (float)(t >> 3);
        }
        float fxv = sx / S - (float)qx;
        float fyv = sy / S - (float)qy;
        int Y = (s1i * 8 + shq * 4 + fy + 2) & 255;
        int X = (s2i * 8 + swq * 4 + fx + 2) & 255;
        size_t base = (size_t)b * 2 * HH * WW;
        f0[base + (size_t)Y * WW + X] = fxv;
        f0[base + (size_t)HH * WW + (size_t)Y * WW + X] = fyv;
    } else if (tid < 97) {
        int rm = tid - 16;
        int a = rm / 9, bc = rm - a * 9;
        float mx = -1e30f;
        for (int t = 0; t < 64; ++t) {
            int h2 = t >> 3, w2 = t & 7;
            int qy = a + 3 - h2, qx = bc + 3 - w2;
            float val = (qy >= 0 && qy < 8 && qx >= 0 && qx < 8) ? cls[(qy * 8 + qx) * 67 + t] : 0.0f;
            mx = fmaxf(mx, val);
        }
        float S = 0.f, sc = 0.f, sx = 0.f, sy = 0.f;
        for (int t = 0; t < 64; ++t) {
            int h2 = t >> 3, w2 = t & 7;
            int qy = a + 3 - h2, qx = bc + 3 - w2;
            float val = (qy >= 0 && qy < 8 && qx >= 0 && qx < 8) ? cls[(qy * 8 + qx) * 67 + t] : 0.0f;
            float p = __expf(val - mx);
            S += p; sc += val * p; sx += p * (float)w2; sy += p * (float)h2;
        }
        cmid[rm] = sc / S;
        fxm[rm] = sx / S - (float)(bc + 3) * 0.5f;
        fym[rm] = sy / S - (float)(a + 3) * 0.5f;
    }
    __syncthreads();

    // flow_mid quadrant combine -> 8x8
    if (tid < 64) {
        int fy = tid >> 3, fx = tid & 7;
        int i00 = fy * 9 + fx, i01 = i00 + 1, i10 = i00 + 9, i11 = i00 + 10;
        float c00 = cmid[i00], c01 = cmid[i01], c10 = cmid[i10], c11 = cmid[i11];
        float m = fmaxf(fmaxf(c00, c01), fmaxf(c10, c11));
        float p0 = __expf(c00 - m), p1 = __expf(c01 - m), p2 = __expf(c10 - m), p3 = __expf(c11 - m);
        float S = p0 + p1 + p2 + p3;
        float ox = 2.0f * (p0 * fxm[i00] + p1 * fxm[i01] + p2 * fxm[i10] + p3 * fxm[i11]) / S;
        float oy = 2.0f * (p0 * fym[i00] + p1 * fym[i01] + p2 * fym[i10] + p3 * fym[i11]) / S;
        int Y = (s1i * 16 + shq * 8 + fy + 4) & 511;
        int X = (s2i * 16 + swq * 8 + fx + 4) & 511;
        size_t base = (size_t)b * 2 * 512 * 512;
        f1[base + (size_t)Y * 512 + X] = ox;
        f1[base + (size_t)512 * 512 + (size_t)Y * 512 + X] = oy;
    }
}

// ---------------------------------------------------------------------------
// K5: bilinear resize (half-pixel, edge clamp) + scale, concat 4 outputs
// ---------------------------------------------------------------------------
__global__ __launch_bounds__(256) void resize_out(
    const float* __restrict__ f1e0, const float* __restrict__ f1e1,
    const float* __restrict__ f0e0, const float* __restrict__ f0e1,
    float* __restrict__ out)
{
    int idx = blockIdx.x * 256 + threadIdx.x;       // 0 .. 16777215
    int o = idx >> 22;
    int rem = idx & 4194303;
    int bc = rem >> 20;                              // b*2+ch
    int Y = (rem >> 10) & 1023;
    int X = rem & 1023;
    const float* src; int n; float invf, sc;
    if (o == 0)      { src = f1e1; n = 512; invf = 0.5f;  sc = 2.f; }
    else if (o == 1) { src = f1e0; n = 512; invf = 0.5f;  sc = 2.f; }
    else if (o == 2) { src = f0e0; n = 256; invf = 0.25f; sc = 4.f; }
    else             { src = f0e1; n = 256; invf = 0.25f; sc = 4.f; }
    float syf = ((float)Y + 0.5f) * invf - 0.5f;
    float sxf = ((float)X + 0.5f) * invf - 0.5f;
    int iy = (int)floorf(syf), ix = (int)floorf(sxf);
    float wy = syf - (float)iy, wx = sxf - (float)ix;
    int y0c = min(max(iy, 0), n - 1), y1c = min(max(iy + 1, 0), n - 1);
    int x0c = min(max(ix, 0), n - 1), x1c = min(max(ix + 1, 0), n - 1);
    const float* s = src + (size_t)bc * n * n;
    float v00 = s[(size_t)y0c * n + x0c], v01 = s[(size_t)y0c * n + x1c];
    float v10 = s[(size_t)y1c * n + x0c], v11 = s[(size_t)y1c * n + x1c];
    float v = (1.f - wy) * ((1.f - wx) * v00 + wx * v01) + wy * ((1.f - wx) * v10 + wx * v11);
    out[idx] = v * sc;
}

// ---------------------------------------------------------------------------
extern "C" void kernel_launch(void* const* d_in, const int* in_sizes, int n_in,
                              void* d_out, int out_size, void* d_ws, size_t ws_size,
                              hipStream_t stream)
{
    const float* feat0 = (const float*)d_in[0];
    const float* feat2 = (const float*)d_in[1];
    const float* wq = (const float*)d_in[2];
    const float* bq = (const float*)d_in[3];
    const float* wk = (const float*)d_in[4];
    const float* bk = (const float*)d_in[5];
    const float* btab = (const float*)d_in[6];

    char* w = (char*)d_ws;
    const size_t F = (size_t)16777216 * 2;   // bytes per bf16 NHWC field (2*256*256*128)
    __hip_bfloat16* q0 = (__hip_bfloat16*)(w);
    __hip_bfloat16* k0 = (__hip_bfloat16*)(w + F);
    __hip_bfloat16* q2 = (__hip_bfloat16*)(w + 2 * F);
    __hip_bfloat16* k2 = (__hip_bfloat16*)(w + 3 * F);
    __hip_bfloat16* in0T = (__hip_bfloat16*)(w + 4 * F);
    __hip_bfloat16* in1T = (__hip_bfloat16*)(w + 5 * F);
    __hip_bfloat16* w2q = (__hip_bfloat16*)(w + 6 * F);
    __hip_bfloat16* w2k = (__hip_bfloat16*)(w + 6 * F + 294912);
    float* f1e0 = (float*)(w + 6 * F + 2 * 294912);
    float* f1e1 = f1e0 + 1048576;   // 2*2*512*512
    float* f0e0 = f1e1 + 1048576;
    float* f0e1 = f0e0 + 262144;    // 2*2*256*256

    hipLaunchKernelGGL(transpose_nhwc, dim3(16384), dim3(256), 0, stream, feat0, in0T);
    hipLaunchKernelGGL(transpose_nhwc, dim3(16384), dim3(256), 0, stream, feat2, in1T);
    hipLaunchKernelGGL(prep_w, dim3(576), dim3(256), 0, stream, wq, wk, w2q, w2k);
    hipLaunchKernelGGL(conv3x3_mfma, dim3(2048, 4), dim3(256), 0, stream,
                       in0T, in1T, w2q, w2k, bq, bk, q0, k0, q2, k2);
    hipLaunchKernelGGL(window_flow, dim3(2048, 8), dim3(256), 0, stream,
                       q0, k0, q2, k2, btab, f1e0, f1e1, f0e0, f0e1);
    hipLaunchKernelGGL(resize_out, dim3(65536), dim3(256), 0, stream,
                       f1e0, f1e1, f0e0, f0e1, (float*)d_out);
}

// Round 2
// 695.541 us; speedup vs baseline: 1.3188x; 1.3188x over previous
//
#include <hip/hip_runtime.h>
#include <hip/hip_bf16.h>
#include <math.h>

typedef __attribute__((ext_vector_type(8))) __bf16 bf16x8;
typedef __attribute__((ext_vector_type(4))) float f32x4;

#define HH 256
#define WW 256
#define SCALEF 0.08838834764831845f  // 128^-0.5

// ---------------------------------------------------------------------------
// K1: NCHW f32 -> NHWC bf16 transpose
// ---------------------------------------------------------------------------
__global__ __launch_bounds__(256) void transpose_nhwc(const float* __restrict__ in,
                                                      __hip_bfloat16* __restrict__ out)
{
    int blk = blockIdx.x;
    int c0 = (blk & 3) * 32;
    int x0 = ((blk >> 2) & 7) * 32;
    int by = blk >> 5;              // b*256 + y
    int y = by & 255, b = by >> 8;
    __shared__ float tile[32][33];
    int tx = threadIdx.x & 31, ty = threadIdx.x >> 5;   // ty 0..7
#pragma unroll
    for (int i = 0; i < 4; i++) {
        int c = c0 + ty + 8 * i;
        tile[ty + 8 * i][tx] = in[(((size_t)b * 128 + c) * HH + y) * WW + x0 + tx];
    }
    __syncthreads();
#pragma unroll
    for (int i = 0; i < 4; i++) {
        int x = x0 + ty + 8 * i;
        out[(((size_t)b * HH + y) * WW + x) * 128 + c0 + tx] =
            __float2bfloat16(tile[tx][ty + 8 * i]);
    }
}

// ---------------------------------------------------------------------------
// K2: weight repack (co,ci,ky,kx) f32 -> W2[co][ (ky*3+kx)*128 + ci ] bf16
// ---------------------------------------------------------------------------
__global__ __launch_bounds__(256) void prep_w(const float* __restrict__ wq,
                                              const float* __restrict__ wk,
                                              __hip_bfloat16* __restrict__ w2q,
                                              __hip_bfloat16* __restrict__ w2k)
{
    int i = blockIdx.x * 256 + threadIdx.x;
    if (i >= 128 * 128 * 9) return;
    int co = i / (128 * 9);
    int r = i - co * 128 * 9;
    int ci = r / 9;
    int t = r - ci * 9;
    int dst = co * 1152 + t * 128 + ci;
    w2q[dst] = __float2bfloat16(wq[i]);
    w2k[dst] = __float2bfloat16(wk[i]);
}

// ---------------------------------------------------------------------------
// K3: conv3x3 (SAME) as implicit GEMM with MFMA bf16.
// Block: 8x8 pixel tile, all 128 co. 4 waves, wave w owns co [32w,32w+32).
// ---------------------------------------------------------------------------
#define CPAD 152   // 128 + 24 pad: 304B rows, 16B-aligned, ~2-way banks
__global__ __launch_bounds__(256, 4) void conv3x3_mfma(
    const __hip_bfloat16* __restrict__ in0, const __hip_bfloat16* __restrict__ in1,
    const __hip_bfloat16* __restrict__ w2q, const __hip_bfloat16* __restrict__ w2k,
    const float* __restrict__ bq, const float* __restrict__ bk,
    __hip_bfloat16* __restrict__ q0, __hip_bfloat16* __restrict__ k0,
    __hip_bfloat16* __restrict__ q2, __hip_bfloat16* __restrict__ k2)
{
    const int cid = blockIdx.y;
    const __hip_bfloat16* src = (cid >= 2) ? in1 : in0;
    const __hip_bfloat16* wmat = (cid & 1) ? w2k : w2q;
    const float* bias = (cid & 1) ? bk : bq;
    __hip_bfloat16* dst = (cid == 0) ? q0 : (cid == 1) ? k0 : (cid == 2) ? q2 : k2;

    const int pix = blockIdx.x;           // 0..2047
    const int b = pix >> 10;
    const int rr = pix & 1023;
    const int y0 = (rr >> 5) << 3;
    const int x0 = (rr & 31) << 3;

    __shared__ __align__(16) __hip_bfloat16 patch[100 * CPAD];

    for (int idx = threadIdx.x; idx < 1600; idx += 256) {
        int p = idx >> 4, lc = idx & 15;
        int py = p / 10, px = p - py * 10;
        int gy = y0 + py - 1, gx = x0 + px - 1;
        uint4 v = make_uint4(0u, 0u, 0u, 0u);
        if (gy >= 0 && gy < HH && gx >= 0 && gx < WW)
            v = *(const uint4*)(src + ((((size_t)b * HH + gy) * WW + gx) << 7) + lc * 8);
        *(uint4*)(patch + p * CPAD + lc * 8) = v;
    }
    __syncthreads();

    const int lane = threadIdx.x & 63;
    const int wv = threadIdx.x >> 6;
    const int l15 = lane & 15;
    const int kq = lane >> 4;

    f32x4 acc[4][2];
#pragma unroll
    for (int mi = 0; mi < 4; mi++)
#pragma unroll
        for (int n = 0; n < 2; n++) acc[mi][n] = (f32x4){0.f, 0.f, 0.f, 0.f};

    const __hip_bfloat16* wcol0 = wmat + (size_t)(wv * 32 + l15) * 1152;
    const __hip_bfloat16* wcol1 = wmat + (size_t)(wv * 32 + 16 + l15) * 1152;

    for (int t = 0; t < 9; ++t) {
        int ky = t / 3, kx = t - ky * 3;
#pragma unroll
        for (int cc = 0; cc < 4; ++cc) {
            int k = t * 128 + cc * 32 + kq * 8;
            bf16x8 b0 = *(const bf16x8*)(wcol0 + k);
            bf16x8 b1 = *(const bf16x8*)(wcol1 + k);
#pragma unroll
            for (int mi = 0; mi < 4; ++mi) {
                int m = mi * 16 + l15;
                int my = m >> 3, mx = m & 7;
                bf16x8 a = *(const bf16x8*)(patch + ((my + ky) * 10 + (mx + kx)) * CPAD + cc * 32 + kq * 8);
                acc[mi][0] = __builtin_amdgcn_mfma_f32_16x16x32_bf16(a, b0, acc[mi][0], 0, 0, 0);
                acc[mi][1] = __builtin_amdgcn_mfma_f32_16x16x32_bf16(a, b1, acc[mi][1], 0, 0, 0);
            }
        }
    }

    float bv0 = bias[wv * 32 + l15];
    float bv1 = bias[wv * 32 + 16 + l15];
#pragma unroll
    for (int mi = 0; mi < 4; ++mi) {
#pragma unroll
        for (int r = 0; r < 4; ++r) {
            int m = mi * 16 + kq * 4 + r;
            int my = m >> 3, mx = m & 7;
            size_t base = (((size_t)b * HH + (y0 + my)) * WW + (x0 + mx)) << 7;
            dst[base + wv * 32 + l15] = __float2bfloat16(acc[mi][0][r] + bv0);
            dst[base + wv * 32 + 16 + l15] = __float2bfloat16(acc[mi][1][r] + bv1);
        }
    }
}

// ---------------------------------------------------------------------------
// K4: per-(window, estimate x shift) correlation + flow_bsd + flow_mid
// writes spliced+rolled flow fields directly.
// Softmax phases are wave-parallel: 16-lane groups per row, shfl_xor reduce.
// ---------------------------------------------------------------------------
#define WPAD 136     // 272B rows: 16B-aligned, stride 4 dwords mod 32 -> 2-way (free)
#define CST 66       // cls row stride (floats)
__global__ __launch_bounds__(256, 3) void window_flow(
    const __hip_bfloat16* __restrict__ q0, const __hip_bfloat16* __restrict__ k0,
    const __hip_bfloat16* __restrict__ q2, const __hip_bfloat16* __restrict__ k2,
    const float* __restrict__ btab,
    float* __restrict__ f1e0, float* __restrict__ f1e1,
    float* __restrict__ f0e0, float* __restrict__ f0e1)
{
    const int combo = blockIdx.y;            // 0..7
    const int e = combo >> 2;
    const int sflag = combo & 3;
    const int shq = (sflag >> 1) & 1;        // shift_h flag == quadrant y
    const int swq = sflag & 1;               // shift_w flag == quadrant x
    const int sh = shq ? 4 : 0, sw = swq ? 4 : 0;
    const __hip_bfloat16* qf = e ? q2 : q0;
    const __hip_bfloat16* kf = e ? k0 : k2;
    float* f1 = e ? f1e1 : f1e0;
    float* f0 = e ? f0e1 : f0e0;

    const int wdx = blockIdx.x;              // 0..2047
    const int b = wdx >> 10;
    const int s1i = (wdx >> 5) & 31;
    const int s2i = wdx & 31;

    __shared__ __align__(16) __hip_bfloat16 qt[64 * WPAD];
    __shared__ __align__(16) __hip_bfloat16 kt[64 * WPAD];
    __shared__ float cls[64 * CST];
    __shared__ float cmid[81], fxm[81], fym[81];
    __shared__ float sb[225];

    const int tid = threadIdx.x;
    if (tid < 225) sb[tid] = btab[tid];

    for (int idx = tid; idx < 2048; idx += 256) {
        int which = idx >> 10;
        int p = (idx >> 4) & 63, lc = idx & 15;
        int iy = p >> 3, ix = p & 7;
        int gy = (s1i * 8 + iy + sh) & 255;
        int gx = (s2i * 8 + ix + sw) & 255;
        const __hip_bfloat16* srcf = which ? kf : qf;
        uint4 v = *(const uint4*)(srcf + ((((size_t)b * HH + gy) * WW + gx) << 7) + lc * 8);
        __hip_bfloat16* dstt = which ? kt : qt;
        *(uint4*)(dstt + p * WPAD + lc * 8) = v;
    }
    __syncthreads();

    // corr = qw . kw^T   (M=64, N=64, K=128), 4 waves over M
    const int lane = tid & 63;
    const int wv = tid >> 6;
    const int l15 = lane & 15;
    const int kq = lane >> 4;

    f32x4 acc[4];
#pragma unroll
    for (int nf = 0; nf < 4; nf++) acc[nf] = (f32x4){0.f, 0.f, 0.f, 0.f};

#pragma unroll
    for (int kc = 0; kc < 4; ++kc) {
        bf16x8 a = *(const bf16x8*)(qt + (wv * 16 + l15) * WPAD + kc * 32 + kq * 8);
#pragma unroll
        for (int nf = 0; nf < 4; ++nf) {
            bf16x8 bb = *(const bf16x8*)(kt + (nf * 16 + l15) * WPAD + kc * 32 + kq * 8);
            acc[nf] = __builtin_amdgcn_mfma_f32_16x16x32_bf16(a, bb, acc[nf], 0, 0, 0);
        }
    }

    // epilogue: scale + relative-pos bias + shift mask -> cls
#pragma unroll
    for (int nf = 0; nf < 4; ++nf) {
#pragma unroll
        for (int r = 0; r < 4; ++r) {
            int row = wv * 16 + kq * 4 + r;
            int col = nf * 16 + l15;
            int qy = row >> 3, qx = row & 7;
            int ty = col >> 3, tx = col & 7;
            float v = acc[nf][r] * SCALEF + sb[(qy - ty + 7) * 15 + (qx - tx + 7)];
            if (sflag) {
                int rhq = 0, rwq = 0, rht = 0, rwt = 0;
                if (shq && s1i == 31) { rhq = (qy < 4) ? 1 : 2; rht = (ty < 4) ? 1 : 2; }
                if (swq && s2i == 31) { rwq = (qx < 4) ? 1 : 2; rwt = (tx < 4) ? 1 : 2; }
                int regq, regt;
                if (shq && swq) { regq = rhq * 3 + rwq; regt = rht * 3 + rwt; }
                else if (shq)   { regq = rhq; regt = rht; }
                else            { regq = rwq; regt = rwt; }
                if (regq != regt) v -= 10000.0f;
            }
            cls[row * CST + col] = v;
        }
    }
    __syncthreads();

    const int rg = tid >> 4;       // 16 row-groups
    const int lg = tid & 15;       // 16 lanes per row

    // ---- flow_bsd: 16 rows, one 16-lane group each, 4 cols/lane ----
    {
        int fy = rg >> 2, fx = rg & 3;
        int qy = fy + 2, qx = fx + 2;
        const float* rowp = &cls[(qy * 8 + qx) * CST];
        float v[4];
        float mx = -1e30f;
#pragma unroll
        for (int j = 0; j < 4; ++j) { v[j] = rowp[lg + 16 * j]; mx = fmaxf(mx, v[j]); }
#pragma unroll
        for (int m = 8; m >= 1; m >>= 1) mx = fmaxf(mx, __shfl_xor(mx, m));
        float S = 0.f, sx = 0.f, sy = 0.f;
#pragma unroll
        for (int j = 0; j < 4; ++j) {
            int t = lg + 16 * j;
            float p = __expf(v[j] - mx);
            S += p; sx += p * (float)(t & 7); sy += p * (float)(t >> 3);
        }
#pragma unroll
        for (int m = 8; m >= 1; m >>= 1) {
            S += __shfl_xor(S, m); sx += __shfl_xor(sx, m); sy += __shfl_xor(sy, m);
        }
        if (lg == 0) {
            float fxv = sx / S - (float)qx;
            float fyv = sy / S - (float)qy;
            int Y = (s1i * 8 + shq * 4 + fy + 2) & 255;
            int X = (s2i * 8 + swq * 4 + fx + 2) & 255;
            size_t base = (size_t)b * 2 * HH * WW;
            f0[base + (size_t)Y * WW + X] = fxv;
            f0[base + (size_t)HH * WW + (size_t)Y * WW + X] = fyv;
        }
    }

    // ---- flow_mid row softmaxes: 81 rows, 16 at a time ----
    for (int it = 0; it < 6; ++it) {
        int rm = it * 16 + rg;
        if (rm < 81) {
            int a = rm / 9, bc = rm - a * 9;
            float v[4];
            float mx = -1e30f;
#pragma unroll
            for (int j = 0; j < 4; ++j) {
                int t = lg + 16 * j;
                int h2 = t >> 3, w2 = t & 7;
                int qy = a + 3 - h2, qx = bc + 3 - w2;
                v[j] = (qy >= 0 && qy < 8 && qx >= 0 && qx < 8) ? cls[(qy * 8 + qx) * CST + t] : 0.0f;
                mx = fmaxf(mx, v[j]);
            }
#pragma unroll
            for (int m = 8; m >= 1; m >>= 1) mx = fmaxf(mx, __shfl_xor(mx, m));
            float S = 0.f, sc = 0.f, sx = 0.f, sy = 0.f;
#pragma unroll
            for (int j = 0; j < 4; ++j) {
                int t = lg + 16 * j;
                float p = __expf(v[j] - mx);
                S += p; sc += v[j] * p; sx += p * (float)(t & 7); sy += p * (float)(t >> 3);
            }
#pragma unroll
            for (int m = 8; m >= 1; m >>= 1) {
                S += __shfl_xor(S, m); sc += __shfl_xor(sc, m);
                sx += __shfl_xor(sx, m); sy += __shfl_xor(sy, m);
            }
            if (lg == 0) {
                float inv = 1.0f / S;
                cmid[rm] = sc * inv;
                fxm[rm] = sx * inv - (float)(bc + 3) * 0.5f;
                fym[rm] = sy * inv - (float)(a + 3) * 0.5f;
            }
        }
    }
    __syncthreads();

    // flow_mid quadrant combine -> 8x8
    if (tid < 64) {
        int fy = tid >> 3, fx = tid & 7;
        int i00 = fy * 9 + fx, i01 = i00 + 1, i10 = i00 + 9, i11 = i00 + 10;
        float c00 = cmid[i00], c01 = cmid[i01], c10 = cmid[i10], c11 = cmid[i11];
        float m = fmaxf(fmaxf(c00, c01), fmaxf(c10, c11));
        float p0 = __expf(c00 - m), p1 = __expf(c01 - m), p2 = __expf(c10 - m), p3 = __expf(c11 - m);
        float S = p0 + p1 + p2 + p3;
        float ox = 2.0f * (p0 * fxm[i00] + p1 * fxm[i01] + p2 * fxm[i10] + p3 * fxm[i11]) / S;
        float oy = 2.0f * (p0 * fym[i00] + p1 * fym[i01] + p2 * fym[i10] + p3 * fym[i11]) / S;
        int Y = (s1i * 16 + shq * 8 + fy + 4) & 511;
        int X = (s2i * 16 + swq * 8 + fx + 4) & 511;
        size_t base = (size_t)b * 2 * 512 * 512;
        f1[base + (size_t)Y * 512 + X] = ox;
        f1[base + (size_t)512 * 512 + (size_t)Y * 512 + X] = oy;
    }
}

// ---------------------------------------------------------------------------
// K5: bilinear resize (half-pixel, edge clamp) + scale, concat 4 outputs
// ---------------------------------------------------------------------------
__global__ __launch_bounds__(256) void resize_out(
    const float* __restrict__ f1e0, const float* __restrict__ f1e1,
    const float* __restrict__ f0e0, const float* __restrict__ f0e1,
    float* __restrict__ out)
{
    int idx = blockIdx.x * 256 + threadIdx.x;       // 0 .. 16777215
    int o = idx >> 22;
    int rem = idx & 4194303;
    int bc = rem >> 20;                              // b*2+ch
    int Y = (rem >> 10) & 1023;
    int X = rem & 1023;
    const float* src; int n; float invf, sc;
    if (o == 0)      { src = f1e1; n = 512; invf = 0.5f;  sc = 2.f; }
    else if (o == 1) { src = f1e0; n = 512; invf = 0.5f;  sc = 2.f; }
    else if (o == 2) { src = f0e0; n = 256; invf = 0.25f; sc = 4.f; }
    else             { src = f0e1; n = 256; invf = 0.25f; sc = 4.f; }
    float syf = ((float)Y + 0.5f) * invf - 0.5f;
    float sxf = ((float)X + 0.5f) * invf - 0.5f;
    int iy = (int)floorf(syf), ix = (int)floorf(sxf);
    float wy = syf - (float)iy, wx = sxf - (float)ix;
    int y0c = min(max(iy, 0), n - 1), y1c = min(max(iy + 1, 0), n - 1);
    int x0c = min(max(ix, 0), n - 1), x1c = min(max(ix + 1, 0), n - 1);
    const float* s = src + (size_t)bc * n * n;
    float v00 = s[(size_t)y0c * n + x0c], v01 = s[(size_t)y0c * n + x1c];
    float v10 = s[(size_t)y1c * n + x0c], v11 = s[(size_t)y1c * n + x1c];
    float v = (1.f - wy) * ((1.f - wx) * v00 + wx * v01) + wy * ((1.f - wx) * v10 + wx * v11);
    out[idx] = v * sc;
}

// ---------------------------------------------------------------------------
extern "C" void kernel_launch(void* const* d_in, const int* in_sizes, int n_in,
                              void* d_out, int out_size, void* d_ws, size_t ws_size,
                              hipStream_t stream)
{
    const float* feat0 = (const float*)d_in[0];
    const float* feat2 = (const float*)d_in[1];
    const float* wq = (const float*)d_in[2];
    const float* bq = (const float*)d_in[3];
    const float* wk = (const float*)d_in[4];
    const float* bk = (const float*)d_in[5];
    const float* btab = (const float*)d_in[6];

    char* w = (char*)d_ws;
    const size_t F = (size_t)16777216 * 2;   // bytes per bf16 NHWC field (2*256*256*128)
    __hip_bfloat16* q0 = (__hip_bfloat16*)(w);
    __hip_bfloat16* k0 = (__hip_bfloat16*)(w + F);
    __hip_bfloat16* q2 = (__hip_bfloat16*)(w + 2 * F);
    __hip_bfloat16* k2 = (__hip_bfloat16*)(w + 3 * F);
    __hip_bfloat16* in0T = (__hip_bfloat16*)(w + 4 * F);
    __hip_bfloat16* in1T = (__hip_bfloat16*)(w + 5 * F);
    __hip_bfloat16* w2q = (__hip_bfloat16*)(w + 6 * F);
    __hip_bfloat16* w2k = (__hip_bfloat16*)(w + 6 * F + 294912);
    float* f1e0 = (float*)(w + 6 * F + 2 * 294912);
    float* f1e1 = f1e0 + 1048576;   // 2*2*512*512
    float* f0e0 = f1e1 + 1048576;
    float* f0e1 = f0e0 + 262144;    // 2*2*256*256

    hipLaunchKernelGGL(transpose_nhwc, dim3(16384), dim3(256), 0, stream, feat0, in0T);
    hipLaunchKernelGGL(transpose_nhwc, dim3(16384), dim3(256), 0, stream, feat2, in1T);
    hipLaunchKernelGGL(prep_w, dim3(576), dim3(256), 0, stream, wq, wk, w2q, w2k);
    hipLaunchKernelGGL(conv3x3_mfma, dim3(2048, 4), dim3(256), 0, stream,
                       in0T, in1T, w2q, w2k, bq, bk, q0, k0, q2, k2);
    hipLaunchKernelGGL(window_flow, dim3(2048, 8), dim3(256), 0, stream,
                       q0, k0, q2, k2, btab, f1e0, f1e1, f0e0, f0e1);
    hipLaunchKernelGGL(resize_out, dim3(65536), dim3(256), 0, stream,
                       f1e0, f1e1, f0e0, f0e1, (float*)d_out);
}